// Round 5
// baseline (363.580 us; speedup 1.0000x reference)
//
#include <hip/hip_runtime.h>

// FogAdversary: diamond-square fractal fog + blend — SINGLE fused kernel.
// Grid 512 = 2 blocks per batch (half = bx&1), 1024 threads.
// LDS: Bm (full 128x128 C lattice, 64KB) + sD (29 D-rows, 14.5KB) = 78.5KB
//   -> exactly 2 blocks/CU, 32 waves/CU, one residency round (512 = 2*256 CUs).
// Each block: (1) levels 0..6 of the recursion in Bm (redundant per half, ~µs),
//             (2) two 56-row chunks: build sD (level-7 centers), then stream
//                 crop+blend with float4 I/O and non-temporal output stores.
//
// Map conventions (per reference):
//   level k: step s=256>>k, h=s/2, wibble w_k = 2^-k, fog vars v=3k..3k+2
//   center  m[h::s, h::s] = (C[i,j]+C[i+1,j]+C[i,j+1]+C[i+1,j+1])/4 + w*f[3k]
//   lt      m[0::s, h::s] = (D[i,j]+D[i-1,j]+C[i,j]+C[i,j+1])/4     + w*f[3k+1]
//   tt      m[h::s, 0::s] = (D[i,j]+D[i,j-1]+C[i,j]+C[i+1,j])/4     + w*f[3k+2]
//   (indices mod n; crop region (PAD=16) never wraps rows/cols at level 7)
// Bm[r][c] holds m[2r][2c] (the even-even lattice = level-7 corners C).

#define MAPB 128

typedef float vf4 __attribute__((ext_vector_type(4)));  // native vec for nontemporal

struct FogPtrs { const float* f[24]; };

__global__ __launch_bounds__(1024, 8) void fog_fused(
    FogPtrs fp, const float* __restrict__ inp, float* __restrict__ out)
{
    __shared__ float Bm[MAPB * MAPB];   // 64 KB C lattice
    __shared__ float sD[29 * 128];      // 14.5 KB level-7 centers for one chunk
    const int bx   = blockIdx.x;
    const int b    = bx >> 1;
    const int half = bx & 1;
    const int t    = threadIdx.x;

    if (t == 0) Bm[0] = 0.0f;           // only lattice point never written by a level
    __syncthreads();

    // ---- levels 0..5 (nn = 1..1024): one masked item per thread ----
    float w = 1.0f;
    #pragma unroll
    for (int k = 0; k < 6; ++k) {
        const int n = 1 << k, mask = n - 1;
        const int S = MAPB >> k, H = S >> 1;
        const int nn = n * n;
        if (t < nn) {
            const int i = t >> k, j = t & mask;
            const int i1 = (i + 1) & mask, j1 = (j + 1) & mask;
            const float c00 = Bm[i  * S * MAPB + j  * S];
            const float c10 = Bm[i1 * S * MAPB + j  * S];
            const float c01 = Bm[i  * S * MAPB + j1 * S];
            const float c11 = Bm[i1 * S * MAPB + j1 * S];
            Bm[(i * S + H) * MAPB + j * S + H] =
                (c00 + c10 + c01 + c11) * 0.25f + w * fp.f[3 * k][(size_t)b * nn + t];
        }
        __syncthreads();
        if (t < nn) {
            const int i = t >> k, j = t & mask;
            const int i1 = (i + 1) & mask, j1 = (j + 1) & mask;
            const int im = (i - 1) & mask, jm = (j - 1) & mask;
            const float dij = Bm[(i  * S + H) * MAPB + j  * S + H];
            const float dmi = Bm[(im * S + H) * MAPB + j  * S + H];
            const float dmj = Bm[(i  * S + H) * MAPB + jm * S + H];
            const float c00 = Bm[i  * S * MAPB + j  * S];
            const float c01 = Bm[i  * S * MAPB + j1 * S];
            const float c10 = Bm[i1 * S * MAPB + j  * S];
            Bm[i * S * MAPB + j * S + H] =
                (dij + dmi + c00 + c01) * 0.25f + w * fp.f[3 * k + 1][(size_t)b * nn + t];
            Bm[(i * S + H) * MAPB + j * S] =
                (dij + dmj + c00 + c10) * 0.25f + w * fp.f[3 * k + 2][(size_t)b * nn + t];
        }
        __syncthreads();
        w *= 0.5f;
    }
    // ---- level 6: n=64, S=2, H=1, nn=4096, w=2^-6 ----
    {
        const float w6 = 0.015625f;
        const float* __restrict__ f0 = fp.f[18] + (size_t)b * 4096;
        const float* __restrict__ f1 = fp.f[19] + (size_t)b * 4096;
        const float* __restrict__ f2 = fp.f[20] + (size_t)b * 4096;
        #pragma unroll
        for (int it = 0; it < 4; ++it) {
            const int idx = t + it * 1024;
            const int i = idx >> 6, j = idx & 63;
            const int i1 = (i + 1) & 63, j1 = (j + 1) & 63;
            const float c00 = Bm[i  * 2 * MAPB + j  * 2];
            const float c10 = Bm[i1 * 2 * MAPB + j  * 2];
            const float c01 = Bm[i  * 2 * MAPB + j1 * 2];
            const float c11 = Bm[i1 * 2 * MAPB + j1 * 2];
            Bm[(i * 2 + 1) * MAPB + j * 2 + 1] = (c00 + c10 + c01 + c11) * 0.25f + w6 * f0[idx];
        }
        __syncthreads();
        #pragma unroll
        for (int it = 0; it < 4; ++it) {
            const int idx = t + it * 1024;
            const int i = idx >> 6, j = idx & 63;
            const int i1 = (i + 1) & 63, j1 = (j + 1) & 63;
            const int im = (i - 1) & 63, jm = (j - 1) & 63;
            const float dij = Bm[(i  * 2 + 1) * MAPB + j  * 2 + 1];
            const float dmi = Bm[(im * 2 + 1) * MAPB + j  * 2 + 1];
            const float dmj = Bm[(i  * 2 + 1) * MAPB + jm * 2 + 1];
            const float c00 = Bm[i  * 2 * MAPB + j  * 2];
            const float c01 = Bm[i  * 2 * MAPB + j1 * 2];
            const float c10 = Bm[i1 * 2 * MAPB + j  * 2];
            Bm[i * 2 * MAPB + j * 2 + 1]   = (dij + dmi + c00 + c01) * 0.25f + w6 * f1[idx];
            Bm[(i * 2 + 1) * MAPB + j * 2] = (dij + dmj + c00 + c10) * 0.25f + w6 * f2[idx];
        }
        __syncthreads();
    }

    // ---- level 7 + crop + blend, two 56-row chunks ----
    const float w7 = 0.0078125f;        // 2^-7
    const float* __restrict__ f21b = fp.f[21] + (size_t)b * 16384;
    const float* __restrict__ f22b = fp.f[22] + (size_t)b * 16384;
    const float* __restrict__ f23b = fp.f[23] + (size_t)b * 16384;
    #pragma unroll
    for (int c = 0; c < 2; ++c) {
        const int r0  = half * 112 + c * 56;    // output row base
        const int ci0 = (r0 >> 1) + 7;          // first C row needed
        // D rows ci0..ci0+28 (29 rows); reads Bm rows ci0..ci0+29 (<=120<128)
        for (int idx = t; idx < 29 * 128; idx += 1024) {
            const int di = idx >> 7, j = idx & 127;
            const int j1 = (j + 1) & 127;       // col wrap = map semantics (unused cols harmless)
            const int gr = ci0 + di;
            sD[idx] = (Bm[gr * 128 + j]  + Bm[(gr + 1) * 128 + j] +
                       Bm[gr * 128 + j1] + Bm[(gr + 1) * 128 + j1]) * 0.25f
                      + w7 * f21b[gr * 128 + j];
        }
        __syncthreads();
        // Pair = two adjacent 2x2 quads -> 4 cols x 2 rows -> float4 I/O.
        for (int p = t; p < 28 * 56; p += 1024) {
            const int pr = p / 56;
            const int pc = p - pr * 56;
            const int di = pr + 1;                  // local D row
            const int j0 = 2 * pc + 8;              // map col (8..118, even)
            const int gi = ci0 + di;                // global C row
            const float c0  = Bm[gi * 128 + j0];
            const float c1  = Bm[gi * 128 + j0 + 1];
            const float c2  = Bm[gi * 128 + j0 + 2];
            const float cb0 = Bm[(gi + 1) * 128 + j0];
            const float cb1 = Bm[(gi + 1) * 128 + j0 + 1];
            const float dm  = sD[di * 128 + j0 - 1];
            const float d0  = sD[di * 128 + j0];
            const float d1  = sD[di * 128 + j0 + 1];
            const float du0 = sD[(di - 1) * 128 + j0];
            const float du1 = sD[(di - 1) * 128 + j0 + 1];
            const float2 v22 = *(const float2*)(f22b + (size_t)gi * 128 + j0);
            const float2 v23 = *(const float2*)(f23b + (size_t)gi * 128 + j0);
            const float lt0 = (d0 + du0 + c0 + c1) * 0.25f + w7 * v22.x;
            const float lt1 = (d1 + du1 + c1 + c2) * 0.25f + w7 * v22.y;
            const float tt0 = (d0 + dm + c0 + cb0) * 0.25f + w7 * v23.x;
            const float tt1 = (d1 + d0 + c1 + cb1) * 0.25f + w7 * v23.y;
            const float fa = fminf(fabsf(c0),  1.0f);
            const float fb = fminf(fabsf(lt0), 1.0f);
            const float fc = fminf(fabsf(c1),  1.0f);
            const float fd = fminf(fabsf(lt1), 1.0f);
            const float fe = fminf(fabsf(tt0), 1.0f);
            const float ff = fminf(fabsf(d0),  1.0f);
            const float fg = fminf(fabsf(tt1), 1.0f);
            const float fh = fminf(fabsf(d1),  1.0f);

            const int orow = r0 + 2 * pr;           // output row (0..222)
            const int ocol = 4 * pc;                // output col (0..220), %4==0
            #pragma unroll
            for (int ch = 0; ch < 3; ++ch) {
                const float g = (ch == 0) ? 0.485f : ((ch == 1) ? 0.45f : 0.406f);
                const size_t base = ((size_t)(b * 3 + ch) * 224 + orow) * 224 + ocol;
                const float4 x0 = *(const float4*)(inp + base);
                const float4 x1 = *(const float4*)(inp + base + 224);
                vf4 o0, o1;
                o0.x = x0.x * (1.0f - fa) + fa * g;
                o0.y = x0.y * (1.0f - fb) + fb * g;
                o0.z = x0.z * (1.0f - fc) + fc * g;
                o0.w = x0.w * (1.0f - fd) + fd * g;
                o1.x = x1.x * (1.0f - fe) + fe * g;
                o1.y = x1.y * (1.0f - ff) + ff * g;
                o1.z = x1.z * (1.0f - fg) + fg * g;
                o1.w = x1.w * (1.0f - fh) + fh * g;
                __builtin_nontemporal_store(o0, (vf4*)(out + base));
                __builtin_nontemporal_store(o1, (vf4*)(out + base + 224));
            }
        }
        __syncthreads();    // before next chunk overwrites sD
    }
}

extern "C" void kernel_launch(void* const* d_in, const int* in_sizes, int n_in,
                              void* d_out, int out_size, void* d_ws, size_t ws_size,
                              hipStream_t stream) {
    (void)in_sizes; (void)n_in; (void)out_size; (void)d_ws; (void)ws_size;
    const float* inp = (const float*)d_in[0];
    FogPtrs fp;
    for (int v = 0; v < 24; ++v) fp.f[v] = (const float*)d_in[1 + v];
    fog_fused<<<dim3(512), dim3(1024), 0, stream>>>(fp, inp, (float*)d_out);
}